// Round 2
// baseline (578.200 us; speedup 1.0000x reference)
//
#include <hip/hip_runtime.h>
#include <cfloat>
#include <cmath>

#define V 128000
#define B 256
#define L 256
#define NB 21
#define CAPV 6144      // candidate cap (elements in bins >= collect floor)
#define RCAP 768       // raw-top20 candidate cap
#define NSMALL 1024    // O(n^2) rank path limit; above -> bit-bisection path
static constexpr float EPSF = 1e-5f;

// ---------------- Threefry-2x32-20, JAX partitionable mode ----------------
// key = (0,42); element i (uint64, hi=0): bits = out0 ^ out1 of threefry((0,42),(0,i))
__device__ __forceinline__ unsigned rotl32(unsigned x, int r) {
  return (x << r) | (x >> (32 - r));
}
__device__ __forceinline__ unsigned tf_bits(unsigned e) {
  const unsigned k0 = 0u, k1 = 42u;
  const unsigned k2 = k0 ^ k1 ^ 0x1BD11BDAu;
  unsigned x0 = 0u + k0;
  unsigned x1 = e + k1;
#define TF_RND(r) { x0 += x1; x1 = rotl32(x1, r); x1 ^= x0; }
  TF_RND(13) TF_RND(15) TF_RND(26) TF_RND(6)
  x0 += k1; x1 += k2 + 1u;
  TF_RND(17) TF_RND(29) TF_RND(16) TF_RND(24)
  x0 += k2; x1 += k0 + 2u;
  TF_RND(13) TF_RND(15) TF_RND(26) TF_RND(6)
  x0 += k0; x1 += k1 + 3u;
  TF_RND(17) TF_RND(29) TF_RND(16) TF_RND(24)
  x0 += k1; x1 += k2 + 4u;
  TF_RND(13) TF_RND(15) TF_RND(26) TF_RND(6)
  x0 += k2; x1 += k0 + 5u;
#undef TF_RND
  return x0 ^ x1;
}
__device__ __forceinline__ float gumbelf(unsigned e) {
  unsigned bits = tf_bits(e);
  float f = __uint_as_float((bits >> 9) | 0x3F800000u) - 1.0f;   // [0,1)
  float u = f + 1e-10f;        // JAX: f*(1.0-1e-10 -> rounds to 1.0f) + 1e-10
  u = fmaxf(u, 1e-10f);
  return -logf(-logf(u));
}

// order-preserving float->uint key
__device__ __forceinline__ unsigned flipkey(float v) {
  unsigned u = __float_as_uint(v);
  return (u & 0x80000000u) ? ~u : (u | 0x80000000u);
}
__device__ __forceinline__ float unflip(unsigned k) {
  return __uint_as_float((k & 0x80000000u) ? (k ^ 0x80000000u) : ~k);
}

// ---------------- LDS layout (dynamic, byte offsets) ----------------------
#define OFF_HCNT 0         // u32[4096] count hist (12-bit key)  -> desc-incl prefix
#define OFF_HSUM 16384     // f32[4096] expsum hist (K==0 only)  -> desc-incl prefix
#define OFF_HRAW 32768     // u32[1024] raw hist (10-bit key)    -> desc-incl prefix
#define OFF_LX   36864     // f32[CAPV] candidate values
#define OFF_LI   61440     // i32[CAPV] candidate indices
#define OFF_LE   86016     // f32[CAPV] candidate exp(values)
#define OFF_RX   110592    // f32[RCAP] raw candidates
#define OFF_RXI  113664    // i32[RCAP] raw candidate indices
#define OFF_HK   116736    // i32[1024] hash keys (penalized token ids)
#define OFF_HV   120832    // f32[1024] hash vals (penalized v)
#define OFF_STG  124928    // 128B reduce/scan staging (16 x 8B)
#define OFF_SCL  125056    // scalars
#define SMEM_SZ  125312

struct Scal {
  int bk, bp0, bstar, bR, b2, nv, nr, n2;
  float kth;
  int pad;
};

// ---------------- block reduce helpers (3 barriers each) ------------------
__device__ __forceinline__ double bredd(double x, void* stg, int t) {
  double* s = (double*)stg;
  for (int o = 32; o; o >>= 1) x += __shfl_down(x, o, 64);
  if ((t & 63) == 0) s[t >> 6] = x;
  __syncthreads();
  if (t < 64) {
    double y = (t < 16) ? s[t] : 0.0;
    for (int o = 8; o; o >>= 1) y += __shfl_down(y, o, 64);
    if (t == 0) s[0] = y;
  }
  __syncthreads();
  double r = s[0];
  __syncthreads();
  return r;
}
__device__ __forceinline__ float bredminf(float x, void* stg, int t) {
  float* s = (float*)stg;
  for (int o = 32; o; o >>= 1) x = fminf(x, __shfl_down(x, o, 64));
  if ((t & 63) == 0) s[t >> 6] = x;
  __syncthreads();
  if (t < 64) {
    float y = (t < 16) ? s[t] : FLT_MAX;
    for (int o = 8; o; o >>= 1) y = fminf(y, __shfl_down(y, o, 64));
    if (t == 0) s[0] = y;
  }
  __syncthreads();
  float r = s[0];
  __syncthreads();
  return r;
}
// argmax by (value desc, index asc) — order-independent => deterministic
__device__ __forceinline__ void bredargmax(float v, int i, void* stg, int t,
                                           float& ov, int& oi) {
  float* sv = (float*)stg; int* si = (int*)stg + 16;
  for (int o = 32; o; o >>= 1) {
    float v2 = __shfl_down(v, o, 64); int i2 = __shfl_down(i, o, 64);
    if (v2 > v || (v2 == v && i2 < i)) { v = v2; i = i2; }
  }
  if ((t & 63) == 0) { sv[t >> 6] = v; si[t >> 6] = i; }
  __syncthreads();
  if (t < 64) {
    float y; int yi;
    if (t < 16) { y = sv[t]; yi = si[t]; } else { y = -FLT_MAX; yi = 0x7FFFFFFF; }
    for (int o = 8; o; o >>= 1) {
      float v2 = __shfl_down(y, o, 64); int i2 = __shfl_down(yi, o, 64);
      if (v2 > y || (v2 == y && i2 < yi)) { y = v2; yi = i2; }
    }
    if (t == 0) { sv[0] = y; si[0] = yi; }
  }
  __syncthreads();
  ov = sv[0]; oi = si[0];
  __syncthreads();
}

// in-place descending inclusive prefix: arr[b] = sum_{b' >= b} arr[b']
template <typename T>
__device__ __forceinline__ void scan_desc(T* arr, int nbins, void* stg, int t) {
  T* s = (T*)stg;
  T carry = (T)0;
  for (int base = nbins - 1024; base >= 0; base -= 1024) {
    int bin = base + 1023 - t;                 // t=0 -> highest bin of chunk
    T x = arr[bin];
    for (int o = 1; o < 64; o <<= 1) {         // wave inclusive scan over t
      T y = __shfl_up(x, o, 64);
      if ((t & 63) >= o) x += y;
    }
    if ((t & 63) == 63) s[t >> 6] = x;
    __syncthreads();
    if (t < 64) {                              // scan 16 wave totals
      T y = (t < 16) ? s[t] : (T)0;
      for (int o = 1; o < 16; o <<= 1) {
        T z = __shfl_up(y, o, 64);
        if (t >= o) y += z;
      }
      if (t < 16) s[t] = y;
    }
    __syncthreads();
    T add = (t >= 64) ? s[(t >> 6) - 1] : (T)0;
    arr[bin] = x + add + carry;
    carry = carry + s[15];                     // + chunk total
    __syncthreads();
  }
}

// ---------------- K0: per-row unique penalized tokens ---------------------
extern "C" __global__ void __launch_bounds__(256)
k_penalty(const float* __restrict__ logits, const int* __restrict__ oids,
          const float* __restrict__ rep, const float* __restrict__ freq,
          const float* __restrict__ pres, const float* __restrict__ temp,
          int* __restrict__ wcnt, int* __restrict__ wids, float* __restrict__ wvals)
{
  const int r = blockIdx.x, t = threadIdx.x;
  __shared__ int ids[L];
  __shared__ int cnt;
  if (t == 0) cnt = 0;
  ids[t] = oids[r * L + t];
  __syncthreads();
  const int my = ids[t];
  int c = 0, firstpos = t;
  for (int j = 0; j < L; ++j) {
    int o = ids[j];
    if (o == my) { c++; if (j < firstpos) firstpos = j; }
  }
  if (firstpos == t) {                          // one writer per unique token
    float x = logits[(size_t)r * V + my];
    float rp = rep[r];
    x = (x > 0.f) ? (x / rp) : (x * rp);        // exact ref arithmetic
    x = __fsub_rn(x, __fmul_rn((float)c, freq[r]));
    x = __fsub_rn(x, pres[r]);
    float T = temp[r]; if (T < EPSF) T = 1.f;
    x = x / T;
    int p = atomicAdd(&cnt, 1);
    wids[r * L + p] = my; wvals[r * L + p] = x;
  }
  __syncthreads();
  if (t == 0) wcnt[r] = cnt;
}

// ---------------- K1: fused sampler ---------------------------------------
extern "C" __global__ void __launch_bounds__(1024)
k_fused(const float* __restrict__ logits, const float* __restrict__ temp,
        const int* __restrict__ topk, const float* __restrict__ topp,
        const int* __restrict__ wcnt, const int* __restrict__ wids,
        const float* __restrict__ wvals, float* __restrict__ out)
{
  extern __shared__ char smem[];
  unsigned* hcnt = (unsigned*)(smem + OFF_HCNT);
  float*    hsum = (float*)(smem + OFF_HSUM);
  unsigned* hraw = (unsigned*)(smem + OFF_HRAW);
  float*    lx   = (float*)(smem + OFF_LX);
  int*      li   = (int*)(smem + OFF_LI);
  float*    le   = (float*)(smem + OFF_LE);
  float*    rx   = (float*)(smem + OFF_RX);
  int*      rxi  = (int*)(smem + OFF_RXI);
  int*      hk   = (int*)(smem + OFF_HK);
  float*    hv   = (float*)(smem + OFF_HV);
  void*     stg  = (void*)(smem + OFF_STG);
  Scal*     sc   = (Scal*)(smem + OFF_SCL);

  const int r = blockIdx.x, t = threadIdx.x;
  const float* row = logits + (size_t)r * V;
  const float Traw = temp[r];
  const float T = (Traw < EPSF) ? 1.0f : Traw;
  const int K = topk[r];
  const bool hasK = (K > 0);
  const int keff = hasK ? min(K, V) : V;
  const float tp = topp[r];
  const unsigned ebase = (unsigned)r * (unsigned)V;

  for (int i = t; i < 4096; i += 1024) { hcnt[i] = 0u; hsum[i] = 0.f; }
  hraw[t] = 0u; hk[t] = -1;
  if (t == 0) {
    sc->bk = -1; sc->bp0 = -1; sc->bstar = 4095; sc->bR = 1023;
    sc->b2 = -1; sc->nv = 0; sc->nr = 0; sc->n2 = 0; sc->kth = -FLT_MAX;
  }
  __syncthreads();

  // hash of penalized tokens (open addressing, 1024 slots, load <= 0.25)
  int pc = wcnt[r];
  if (t < pc) {
    int id = wids[r * L + t]; float val = wvals[r * L + t];
    unsigned h = ((unsigned)id * 2654435761u) >> 22;
    while (atomicCAS(&hk[h], -1, id) != -1) h = (h + 1) & 1023u;
    hv[h] = val;
  }
  __syncthreads();

#define PROBE_V(idx, raw, v)                                              \
  {                                                                       \
    v = (raw) / T;                                                        \
    unsigned h_ = ((unsigned)(idx)*2654435761u) >> 22;                    \
    for (;;) {                                                            \
      int k_ = hk[h_];                                                    \
      if (k_ == (idx)) { v = hv[h_]; break; }                             \
      if (k_ == -1) break;                                                \
      h_ = (h_ + 1) & 1023u;                                              \
    }                                                                     \
  }

  // ---- pass A: histograms + raw double-lse (+ deterministic S_all if K==0)
  double dacc = 0.0, sacc = 0.0;
  for (int i4 = t; i4 < V / 4; i4 += 1024) {
    const float4 x = reinterpret_cast<const float4*>(row)[i4];
    const float rv[4] = {x.x, x.y, x.z, x.w};
#pragma unroll
    for (int c = 0; c < 4; ++c) {
      float raw = rv[c]; int idx = i4 * 4 + c;
      float v; PROBE_V(idx, raw, v);
      unsigned fk = flipkey(v);
      atomicAdd(&hcnt[fk >> 20], 1u);
      atomicAdd(&hraw[flipkey(raw) >> 22], 1u);
      dacc += (double)expf(raw);
      if (!hasK) { float ev = expf(v); atomicAdd(&hsum[fk >> 20], ev); sacc += (double)ev; }
    }
  }
  __syncthreads();
  const double lseD = log(bredd(dacc, stg, t));
  const float lseF = (float)lseD;
  double Sall = 0.0;
  if (!hasK) Sall = bredd(sacc, stg, t);

  // ---- descending inclusive prefixes (in place)
  scan_desc<unsigned>(hcnt, 4096, stg, t);
  if (!hasK) scan_desc<float>(hsum, 4096, stg, t);
  scan_desc<unsigned>(hraw, 1024, stg, t);

  // ---- bin finds (all unique-writer parallel searches)
  {
    unsigned incl = hraw[t]; unsigned abv = (t < 1023) ? hraw[t + 1] : 0u;
    if (incl >= 20u && abv < 20u) sc->bR = t;
  }
  for (int b = t; b < 4096; b += 1024) {
    unsigned incl = hcnt[b]; unsigned below = (b > 0) ? hcnt[b - 1] : 0xFFFFFFFFu;
    if (incl <= (unsigned)CAPV && below > (unsigned)CAPV) sc->bstar = b;
  }
  if (hasK) {
    for (int b = t; b < 4096; b += 1024) {
      unsigned incl = hcnt[b]; unsigned abv = (b < 4095) ? hcnt[b + 1] : 0u;
      if (incl >= (unsigned)keff && abv < (unsigned)keff) sc->bk = b;
    }
  } else {
    double PS0 = (double)tp * Sall;
    for (int b = t; b < 4096; b += 1024) {
      double incl = (double)hsum[b];
      double abv = (b < 4095) ? (double)hsum[b + 1] : 0.0;
      if (abv < PS0 && PS0 <= incl) sc->bp0 = b;
    }
  }
  __syncthreads();

  // ---- collect floor & mode (uniform)
  const int f0 = hasK ? sc->bk : sc->bp0;
  const int bstar = sc->bstar;
  int mode, floorV;
  if (!hasK && f0 < 0) { mode = 2; floorV = bstar; }       // PS>=S edge: all survive
  else {
    int fm = (f0 > 0) ? f0 - 1 : 0;                         // 1-bin determinism margin
    if (hcnt[fm] <= (unsigned)CAPV) { mode = 0; floorV = fm; }
    else if (hcnt[f0] <= (unsigned)CAPV) { mode = 0; floorV = f0; }
    else if (hasK) { mode = 0; floorV = bstar; }            // top-keff still inside
    else { mode = 1; floorV = bstar; }                      // K==0 fat-row fallback
  }
  const int bRv = sc->bR;

  // ---- pass B: collect candidates (bins >= floorV) + raw-top20 candidates
  for (int i4 = t; i4 < V / 4; i4 += 1024) {
    const float4 x = reinterpret_cast<const float4*>(row)[i4];
    const float rv[4] = {x.x, x.y, x.z, x.w};
#pragma unroll
    for (int c = 0; c < 4; ++c) {
      float raw = rv[c]; int idx = i4 * 4 + c;
      float v; PROBE_V(idx, raw, v);
      unsigned fk = flipkey(v);
      if ((int)(fk >> 20) >= floorV) {
        int p = atomicAdd(&sc->nv, 1);
        if (p < CAPV) { lx[p] = v; li[p] = idx; le[p] = expf(v); }
      }
      if ((int)(flipkey(raw) >> 22) >= bRv) {
        int p = atomicAdd(&sc->nr, 1);
        if (p < RCAP) { rx[p] = raw; rxi[p] = idx; }
      }
    }
  }
  __syncthreads();
  const int n = min(sc->nv, CAPV);
  const int nr = min(sc->nr, RCAP);

  // ---- raw top-20 (jax.lax.top_k ties -> lower index) + logprob cols 1..20
  if (t < 20) {                                  // safety pad (overwritten below)
    out[B + r * NB + 1 + t] = -INFINITY;
    out[B + B * NB + r * NB + 1 + t] = 0.f;
  }
  __syncthreads();
  for (int j = t; j < nr; j += 1024) {
    float xj = rx[j]; int ij = rxi[j];
    int rank = 0;
    for (int i = 0; i < nr; ++i) {
      float xi = rx[i]; int ii = rxi[i];
      rank += (xi > xj || (xi == xj && ii < ij)) ? 1 : 0;
    }
    if (rank < 20) {
      out[B + r * NB + 1 + rank] = xj - lseF;
      out[B + B * NB + r * NB + 1 + rank] = (float)ij;
    }
  }

  // ---- greedy argmax (global max is always a survivor; it is collected)
  float mg = -FLT_MAX; int mgi = 0x7FFFFFFF;
  for (int j = t; j < n; j += 1024) {
    float xj = lx[j]; int ij = li[j];
    if (xj > mg || (xj == mg && ij < mgi)) { mg = xj; mgi = ij; }
  }
  float gv; int gi;
  bredargmax(mg, mgi, stg, t, gv, gi);

  // ---- exact kth (K>0) and survivor mass S
  float kth = -FLT_MAX;
  double S;
  if (hasK) {
    if (n <= NSMALL) {
      for (int j = t; j < n; j += 1024) {        // rank-count: exact, order-free
        float xj = lx[j];
        int g = 0, e = 0;
        for (int i = 0; i < n; ++i) { float xi = lx[i]; g += (xi > xj); e += (xi == xj); }
        if (g < keff && keff <= g + e) sc->kth = xj;
      }
      __syncthreads();
    } else {                                     // bit-bisection on flipkeys
      unsigned lo = (unsigned)floorV << 20, hi = 0xFFFFFFFFu;
      while (lo < hi) {
        unsigned mid = lo + ((hi - lo) >> 1) + 1;
        double part = 0.0;
        for (int j = t; j < n; j += 1024) part += (flipkey(lx[j]) >= mid) ? 1.0 : 0.0;
        double C = bredd(part, stg, t);
        if (C >= (double)keff) lo = mid; else hi = mid - 1;
      }
      float cand = FLT_MAX;
      for (int j = t; j < n; j += 1024) if (flipkey(lx[j]) >= lo) cand = fminf(cand, lx[j]);
      float kk = bredminf(cand, stg, t);
      if (t == 0) sc->kth = (kk == FLT_MAX) ? unflip((unsigned)floorV << 20) : kk;
      __syncthreads();
    }
    kth = sc->kth;
    if (kth == -FLT_MAX) kth = unflip((unsigned)floorV << 20);  // degraded guard
    double part = 0.0;
    for (int j = t; j < n; j += 1024) if (lx[j] >= kth) part += (double)le[j];
    S = bredd(part, stg, t);
  } else {
    S = Sall;
  }
  const double PS = (double)tp * S;

  // ---- top-p threshold: thr = min{x >= kth : sum_{w > x} e^w < PS}
  float thr;
  if (mode == 0) {
    if (n <= NSMALL) {
      float cand = FLT_MAX;
      for (int j = t; j < n; j += 1024) {
        float xj = lx[j];
        if (xj < kth) continue;
        double G = 0.0;
        for (int i = 0; i < n; ++i) { float xi = lx[i]; if (xi > xj) G += (double)le[i]; }
        if (G < PS) cand = fminf(cand, xj);
      }
      thr = bredminf(cand, stg, t);
      if (thr == FLT_MAX) thr = kth;
    } else {
      unsigned lo = hasK ? flipkey(kth) : ((unsigned)floorV << 20);
      unsigned hi = 0xFFFFFFFFu;
      while (lo < hi) {
        unsigned mid = lo + ((hi - lo) >> 1);
        double part = 0.0;
        for (int j = t; j < n; j += 1024) if (flipkey(lx[j]) > mid) part += (double)le[j];
        double G = bredd(part, stg, t);
        if (G < PS) hi = mid; else lo = mid + 1;
      }
      float cand = FLT_MAX;
      for (int j = t; j < n; j += 1024) if (flipkey(lx[j]) >= lo) cand = fminf(cand, lx[j]);
      thr = bredminf(cand, stg, t);
      if (thr == FLT_MAX) thr = kth;
    }
  } else if (mode == 1) {
    // K==0 fat row: 12-bit sub-histogram of bin bp0, then exact within sub-bin
    const int bp0 = sc->bp0;
    float* sub = (float*)hcnt;                   // hcnt prefix no longer needed
    for (int i = t; i < 4096; i += 1024) sub[i] = 0.f;
    __syncthreads();
    for (int i4 = t; i4 < V / 4; i4 += 1024) {
      const float4 x = reinterpret_cast<const float4*>(row)[i4];
      const float rv[4] = {x.x, x.y, x.z, x.w};
#pragma unroll
      for (int c = 0; c < 4; ++c) {
        float raw = rv[c]; int idx = i4 * 4 + c;
        float v; PROBE_V(idx, raw, v);
        unsigned fk = flipkey(v);
        if ((int)(fk >> 20) == bp0) atomicAdd(&sub[(fk >> 8) & 0xFFFu], expf(v));
      }
    }
    __syncthreads();
    scan_desc<float>(sub, 4096, stg, t);
    const double A0 = (bp0 < 4095) ? (double)hsum[bp0 + 1] : 0.0;
    for (int s2 = t; s2 < 4096; s2 += 1024) {
      double incl = A0 + (double)sub[s2];
      double abv = A0 + ((s2 < 4095) ? (double)sub[s2 + 1] : 0.0);
      if (abv < PS && PS <= incl) sc->b2 = s2;
    }
    __syncthreads();
    const int b2 = sc->b2;
    if (b2 < 0) {
      thr = unflip((unsigned)bp0 << 20);         // whole bin survives (set-exact)
    } else {
      const double A2 = A0 + ((b2 < 4095) ? (double)sub[b2 + 1] : 0.0);
      for (int i4 = t; i4 < V / 4; i4 += 1024) { // collect sub-bin b2 members
        const float4 x = reinterpret_cast<const float4*>(row)[i4];
        const float rv[4] = {x.x, x.y, x.z, x.w};
#pragma unroll
        for (int c = 0; c < 4; ++c) {
          float raw = rv[c]; int idx = i4 * 4 + c;
          float v; PROBE_V(idx, raw, v);
          unsigned fk = flipkey(v);
          if ((int)(fk >> 20) == bp0 && (int)((fk >> 8) & 0xFFFu) == b2) {
            int p = atomicAdd(&sc->n2, 1);
            if (p < CAPV) { lx[p] = v; le[p] = expf(v); }  // greedy already done
          }
        }
      }
      __syncthreads();
      const int n2 = min(sc->n2, CAPV);
      float cand = FLT_MAX;
      for (int j = t; j < n2; j += 1024) {
        float xj = lx[j];
        double G = A2;
        for (int i = 0; i < n2; ++i) { float xi = lx[i]; if (xi > xj) G += (double)le[i]; }
        if (G < PS) cand = fminf(cand, xj);
      }
      thr = bredminf(cand, stg, t);
      if (thr == FLT_MAX)                        // none kept in b2 -> boundary
        thr = unflip(((unsigned)bp0 << 20) | ((unsigned)(b2 + 1) << 8));
    }
  } else {
    thr = -FLT_MAX;                              // mode 2: everything survives
  }

  // ---- gumbel argmax over survivors (v >= thr) ----------------------------
  float yv = -FLT_MAX; int yi = 0x7FFFFFFF;
  if (mode == 0) {
    for (int j = t; j < n; j += 1024) {          // survivors all collected
      float xj = lx[j];
      if (xj >= thr) {
        int ij = li[j];
        float y = xj + gumbelf(ebase + (unsigned)ij);
        if (y > yv || (y == yv && ij < yi)) { yv = y; yi = ij; }
      }
    }
  } else {
    for (int i4 = t; i4 < V / 4; i4 += 1024) {   // rare fallback: scan the row
      const float4 x = reinterpret_cast<const float4*>(row)[i4];
      const float rv[4] = {x.x, x.y, x.z, x.w};
#pragma unroll
      for (int c = 0; c < 4; ++c) {
        float raw = rv[c]; int idx = i4 * 4 + c;
        float v; PROBE_V(idx, raw, v);
        if (v >= thr) {
          float y = v + gumbelf(ebase + (unsigned)idx);
          if (y > yv || (y == yv && idx < yi)) { yv = y; yi = idx; }
        }
      }
    }
  }
  float fy; int fyi;
  bredargmax(yv, yi, stg, t, fy, fyi);

  if (t == 0) {
    int samp = (Traw < EPSF) ? gi : fyi;
    float rawS = row[samp];
    out[r] = (float)samp;                        // sampled_token_ids
    out[B + r * NB] = rawS - lseF;               // logprobs col 0
    out[B + B * NB + r * NB] = (float)samp;      // indices col 0
  }
#undef PROBE_V
}

// ---------------- launch ---------------------------------------------------
extern "C" void kernel_launch(void* const* d_in, const int* in_sizes, int n_in,
                              void* d_out, int out_size, void* d_ws, size_t ws_size,
                              hipStream_t stream) {
  const float* logits = (const float*)d_in[0];
  const float* temp   = (const float*)d_in[1];
  const int*   tkp    = (const int*)d_in[2];
  const float* tpp    = (const float*)d_in[3];
  const float* rep    = (const float*)d_in[4];
  const float* freq   = (const float*)d_in[5];
  const float* pres   = (const float*)d_in[6];
  const int*   oids   = (const int*)d_in[7];
  float* out = (float*)d_out;

  // ws: 4*(256 + 65536 + 65536) = 513 KB
  int*   wcnt  = (int*)d_ws;
  int*   wids  = wcnt + B;
  float* wvals = (float*)(wids + B * L);

  (void)hipFuncSetAttribute((const void*)k_fused,
                            hipFuncAttributeMaxDynamicSharedMemorySize, SMEM_SZ);

  k_penalty<<<B, L, 0, stream>>>(logits, oids, rep, freq, pres, temp,
                                 wcnt, wids, wvals);
  k_fused<<<B, 1024, SMEM_SZ, stream>>>(logits, temp, tkp, tpp,
                                        wcnt, wids, wvals, out);
}